// Round 1
// baseline (134.722 us; speedup 1.0000x reference)
//
#include <hip/hip_runtime.h>

// ---- problem constants ----
#define Bb 32     // batch
#define NN 1024   // H*W = K dim = output cols per channel
#define CC 128    // channels
#define KS 64     // K step per LDS stage
#define MT 128    // m-cols per block (4 waves x 32)

typedef __bf16 bf16x8 __attribute__((ext_vector_type(8)));
typedef float f32x16 __attribute__((ext_vector_type(16)));
typedef float f32x4 __attribute__((ext_vector_type(4)));
typedef unsigned short u16x4 __attribute__((ext_vector_type(4)));
typedef unsigned short u16x8 __attribute__((ext_vector_type(8)));

__device__ __forceinline__ unsigned short f2bf(float f) {
    unsigned u = __builtin_bit_cast(unsigned, f);
    // round-to-nearest-even fp32 -> bf16 (inputs are finite; no NaN handling needed)
    u = (u + 0x7FFFu + ((u >> 16) & 1u)) >> 16;
    return (unsigned short)u;
}

// ---------------------------------------------------------------------------
// Pre-pass: inputs [B, N, C] fp32 -> xbf [C, B, N] bf16 (coalesced both sides
// via LDS tile). 512 blocks = 32 b x 16 n-tiles of 64.
// ---------------------------------------------------------------------------
__global__ __launch_bounds__(256) void transpose_x(const float* __restrict__ in,
                                                   unsigned short* __restrict__ xbf) {
    __shared__ float tile[64 * 132];  // 64 n x 128 c, row padded to 132 floats
    const int b  = blockIdx.x >> 4;
    const int n0 = (blockIdx.x & 15) << 6;
    const int t  = threadIdx.x;

    // load phase: 64 n x 128 c floats, coalesced float4
#pragma unroll
    for (int p = 0; p < 8; ++p) {
        int f     = p * 256 + t;       // float4 unit id, 0..2047
        int n_off = f >> 5;            // 0..63
        int c4    = (f & 31) << 2;     // 0,4,...,124
        f32x4 v = *reinterpret_cast<const f32x4*>(in + ((size_t)(b * NN + n0 + n_off) * CC + c4));
        *reinterpret_cast<f32x4*>(&tile[n_off * 132 + c4]) = v;  // 528B rows: 16B aligned
    }
    __syncthreads();

    // write phase: thread t -> channel c = t>>1, half = t&1 covers 32 n
    const int c = t >> 1, half = t & 1;
    const size_t obase = ((size_t)c * Bb + b) * NN + n0;
#pragma unroll
    for (int q = 0; q < 4; ++q) {
        int nb = half * 32 + q * 8;
        u16x8 o;
#pragma unroll
        for (int j = 0; j < 8; ++j) o[j] = f2bf(tile[(nb + j) * 132 + c]);
        *reinterpret_cast<u16x8*>(xbf + obase + nb) = o;  // 16B aligned, contiguous n
    }
}

// ---------------------------------------------------------------------------
// Main GEMM: block = (channel c, m-tile of 128). 4 waves, each owns 32 m cols.
// D[b=32][m=32] += A[b][k] * B[k][m] via v_mfma_f32_32x32x16_bf16.
// W tile (KS x MT fp32) -> regs -> bf16 -> LDS transposed+swizzled [m][kk].
// ---------------------------------------------------------------------------
template <int USE_XBF>
__global__ __launch_bounds__(256) void cwdense(const float* __restrict__ W,
                                               const float* __restrict__ bias,
                                               const float* __restrict__ xin,
                                               const unsigned short* __restrict__ xbf,
                                               float* __restrict__ out) {
    __shared__ unsigned short wlds[MT * KS];  // 16 KB, row = 64 ushorts = 128 B

    // XCD-friendly mapping: XCD x handles c in [16x, 16x+16) for all m-tiles,
    // so output 32B sectors (8 consecutive co = 8 consecutive c) merge in one L2.
    const int x     = blockIdx.x;
    const int xcd   = x & 7;
    const int i     = x >> 3;
    const int c     = xcd * 16 + (i & 15);
    const int mtile = i >> 4;
    const int m0    = mtile * MT;

    const int t    = threadIdx.x;
    const int w    = t >> 6;
    const int lane = t & 63;
    const int lm   = lane & 31;   // A row (b) / B col (m) within tile
    const int lh   = lane >> 5;   // k half: 0 -> k 0..7, 1 -> k 8..15
    const int m_loc = w * 32 + lm;

    const float* wpanel = W + (size_t)c * NN * NN + m0;  // W[c][k][m0..]

    // staging coords: thread owns 2 quads of 4kk x 4m
    const int mq  = t & 31;    // m quad: cols mq*4..mq*4+3
    const int kq2 = t >> 5;    // 0..7 -> kk quads 2*kq2, 2*kq2+1

    f32x16 acc;
#pragma unroll
    for (int r = 0; r < 16; ++r) acc[r] = 0.0f;

    for (int step = 0; step < NN / KS; ++step) {
        const int k0 = step * KS;

        // coalesced global loads: 8 x float4 per thread (32 KB/block in flight)
        f32x4 q[2][4];
#pragma unroll
        for (int qi = 0; qi < 2; ++qi)
#pragma unroll
            for (int r = 0; r < 4; ++r)
                q[qi][r] = *reinterpret_cast<const f32x4*>(
                    wpanel + (size_t)(k0 + (kq2 * 2 + qi) * 4 + r) * NN + mq * 4);

        __syncthreads();  // previous step's B-frag reads done before overwrite

        // in-register 4x4 transpose -> bf16 -> swizzled LDS [m][kk]
#pragma unroll
        for (int qi = 0; qi < 2; ++qi) {
            const int kkbase = (kq2 * 2 + qi) * 4;
#pragma unroll
            for (int j = 0; j < 4; ++j) {
                const int m = mq * 4 + j;
                u16x4 o;
#pragma unroll
                for (int r = 0; r < 4; ++r) o[r] = f2bf(q[qi][r][j]);
                const int slot = (kkbase >> 3) ^ (m & 7) ^ ((m >> 3) & 7);
                // ushort offset: row m (64 us) + 16B slot + position within slot
                *reinterpret_cast<u16x4*>(&wlds[m * 64 + slot * 8 + (kkbase & 7)]) = o;
            }
        }
        __syncthreads();

        // 4 MFMAs covering KS=64
#pragma unroll
        for (int mi = 0; mi < 4; ++mi) {
            const int kk = mi * 16 + lh * 8;
            bf16x8 a;
            if (USE_XBF) {
                a = *reinterpret_cast<const bf16x8*>(
                    xbf + ((size_t)(c * Bb + lm) * NN + k0 + kk));
            } else {
                u16x8 tmp;
#pragma unroll
                for (int e = 0; e < 8; ++e)
                    tmp[e] = f2bf(xin[((size_t)lm * NN + (k0 + kk + e)) * CC + c]);
                a = __builtin_bit_cast(bf16x8, tmp);
            }
            const int slot = (kk >> 3) ^ (m_loc & 7) ^ ((m_loc >> 3) & 7);
            bf16x8 bf = *reinterpret_cast<const bf16x8*>(&wlds[m_loc * 64 + slot * 8]);
            acc = __builtin_amdgcn_mfma_f32_32x32x16_bf16(a, bf, acc, 0, 0, 0);
        }
    }

    // epilogue: bias + relu + store. out[b][m][co], co = 127 - c.
    const int m  = m0 + m_loc;
    const float bv = bias[(size_t)c * NN + m];
    const int co = (CC - 1) - c;
#pragma unroll
    for (int r = 0; r < 16; ++r) {
        const int brow = (r & 3) + 8 * (r >> 2) + 4 * lh;
        float v = acc[r] + bv;
        v = v > 0.0f ? v : 0.0f;
        out[(size_t)brow * (NN * CC) + (size_t)m * CC + co] = v;
    }
}

extern "C" void kernel_launch(void* const* d_in, const int* in_sizes, int n_in,
                              void* d_out, int out_size, void* d_ws, size_t ws_size,
                              hipStream_t stream) {
    const float* xinp = (const float*)d_in[0];
    const float* W    = (const float*)d_in[1];
    const float* bias = (const float*)d_in[2];
    float* out        = (float*)d_out;

    const size_t need = (size_t)CC * Bb * NN * sizeof(unsigned short);  // 8 MB
    if (ws_size >= need) {
        unsigned short* xbf = (unsigned short*)d_ws;
        transpose_x<<<512, 256, 0, stream>>>(xinp, xbf);
        cwdense<1><<<1024, 256, 0, stream>>>(W, bias, xinp, xbf, out);
    } else {
        cwdense<0><<<1024, 256, 0, stream>>>(W, bias, xinp, nullptr, out);
    }
}